// Round 11
// baseline (398.956 us; speedup 1.0000x reference)
//
#include <hip/hip_runtime.h>

#define TT 512
#define BIGS 1.4426950408889634e10f   // BIG(1e10) * log2(e), scaled domain
#define LOG2E 1.4426950408889634f
#define M2L  (-2.0f * 1.4426950408889634f)
#define LN2F 0.69314718055994531f
#define P_SS 16                       // ticks per superstep (barrier period)
#define G_LAG 80                      // band lag in ticks (>= P_SS + 63 + 1)
#define N_SS 51                       // band3 last tick 574 at s=50

typedef _Float16 h2 __attribute__((ext_vector_type(2)));

__device__ __forceinline__ unsigned pk(float a, float b) {
    h2 v; v.x = (_Float16)a; v.y = (_Float16)b;
    return __builtin_bit_cast(unsigned, v);
}

#if __has_builtin(__builtin_amdgcn_fdot2)
#define FDOT2(a, b, c) __builtin_amdgcn_fdot2(__builtin_bit_cast(h2, (a)), \
                                              __builtin_bit_cast(h2, (b)), (c), false)
#else
__device__ __forceinline__ float fdot2_sw(unsigned a, unsigned b, float c) {
    h2 ha = __builtin_bit_cast(h2, a), hb = __builtin_bit_cast(h2, b);
    return c + (float)ha.x * (float)hb.x + (float)ha.y * (float)hb.y;
}
#define FDOT2(a, b, c) fdot2_sw((a), (b), (c))
#endif

// ---------------------------------------------------------------------------
// g-pair packed D layout: group g = i + 2j; tau = g>>1 in [0,766]; par = g&1
// = i&1. Cells (2p, j) and (2p+1, j) with the same (tau, p) form one fp16
// PAIR stored in one dword. p = i>>1 for tau<=511, else i>>1 - (tau-511).
// The column-march DP front at tick tau is exactly group-pair tau -> the DP
// reads ONE aligned coalesced dword per lane per tick. Total 131072 dwords
// per sample (512 KiB) x 64 samples = 32 MiB = ws budget exactly.
// ---------------------------------------------------------------------------
__device__ __forceinline__ int dwoff(int tau) {     // dword offset of pair-group tau
    if (tau <= 256) return (tau * (tau + 1)) >> 1;
    if (tau <= 512) return 32896 + 256 * (tau - 256);
    return 98432 + (((1023 - tau) * (tau - 512)) >> 1);
}
__device__ __forceinline__ int glen(int tau) {      // pairs in group tau
    if (tau <= 255) return tau + 1;
    if (tau <= 511) return 256;
    return 767 - tau;
}

// ---------------------------------------------------------------------------
// Kernel 1: distances -> g-pair packed fp16 (scaled by log2e).
// Block = (sample, p-tile of 64, tau-tile of 32). Thread (lane=p, wq) does
// 8 taus (wq + 4m); per tau: one Z row (LDS) + two X rows (regs) -> 2 dists
// -> 1 dword store (coalesced across lanes).
// ---------------------------------------------------------------------------
__global__ __launch_bounds__(256, 2) void k_dist(const float* __restrict__ X,
                                                 const float* __restrict__ Z,
                                                 unsigned* __restrict__ Dd,
                                                 float* __restrict__ out) {
    const int n  = blockIdx.x;
    const int p0 = blockIdx.y * 64;
    const int t0 = blockIdx.z * 32;
    if (n == 0 && p0 == 0 && t0 == 0 && threadIdx.x == 0) out[0] = 0.0f;
    if (t0 - p0 - 63 > 511) return;      // whole tile j > 511
    if (t0 + 31 - p0 < 0) return;        // whole tile j < 0

    __shared__ uint4 ZL0[96], ZL1[96];   // Z rows fp16-packed (16B stride: clean)
    __shared__ float zs2[96];            // LOG2E * |z|^2
    const int tt = threadIdx.x;
    const int jb = t0 - p0 - 63;         // lowest j touched by the tile
    if (tt < 96) {
        int j = jb + tt; j = j < 0 ? 0 : (j > 511 ? 511 : j);
        const float4* zp = (const float4*)(Z + (size_t)j * 16);
        const float4 a0 = zp[0], a1 = zp[1], a2 = zp[2], a3 = zp[3];
        float sv = 0.0f;
        sv = fmaf(a0.x, a0.x, sv); sv = fmaf(a0.y, a0.y, sv);
        sv = fmaf(a0.z, a0.z, sv); sv = fmaf(a0.w, a0.w, sv);
        sv = fmaf(a1.x, a1.x, sv); sv = fmaf(a1.y, a1.y, sv);
        sv = fmaf(a1.z, a1.z, sv); sv = fmaf(a1.w, a1.w, sv);
        sv = fmaf(a2.x, a2.x, sv); sv = fmaf(a2.y, a2.y, sv);
        sv = fmaf(a2.z, a2.z, sv); sv = fmaf(a2.w, a2.w, sv);
        sv = fmaf(a3.x, a3.x, sv); sv = fmaf(a3.y, a3.y, sv);
        sv = fmaf(a3.z, a3.z, sv); sv = fmaf(a3.w, a3.w, sv);
        ZL0[tt] = make_uint4(pk(a0.x, a0.y), pk(a0.z, a0.w),
                             pk(a1.x, a1.y), pk(a1.z, a1.w));
        ZL1[tt] = make_uint4(pk(a2.x, a2.y), pk(a2.z, a2.w),
                             pk(a3.x, a3.y), pk(a3.z, a3.w));
        zs2[tt] = LOG2E * sv;
    }

    const int lane = tt & 63;
    const int wq   = tt >> 6;            // 0..3
    const int p    = p0 + lane;          // pair index = row i/2, p <= 255
    unsigned Xh[2][8];
    float    xs2[2];
    const float* xp = X + ((size_t)n * TT + 2 * p) * 16;
#pragma unroll
    for (int q = 0; q < 2; ++q) {
        const float4* xr = (const float4*)(xp + q * 16);
        const float4 a0 = xr[0], a1 = xr[1], a2 = xr[2], a3 = xr[3];
        float sv = 0.0f;
        sv = fmaf(a0.x, a0.x, sv); sv = fmaf(a0.y, a0.y, sv);
        sv = fmaf(a0.z, a0.z, sv); sv = fmaf(a0.w, a0.w, sv);
        sv = fmaf(a1.x, a1.x, sv); sv = fmaf(a1.y, a1.y, sv);
        sv = fmaf(a1.z, a1.z, sv); sv = fmaf(a1.w, a1.w, sv);
        sv = fmaf(a2.x, a2.x, sv); sv = fmaf(a2.y, a2.y, sv);
        sv = fmaf(a2.z, a2.z, sv); sv = fmaf(a2.w, a2.w, sv);
        sv = fmaf(a3.x, a3.x, sv); sv = fmaf(a3.y, a3.y, sv);
        sv = fmaf(a3.z, a3.z, sv); sv = fmaf(a3.w, a3.w, sv);
        xs2[q] = LOG2E * sv;
        Xh[q][0] = pk(a0.x, a0.y); Xh[q][1] = pk(a0.z, a0.w);
        Xh[q][2] = pk(a1.x, a1.y); Xh[q][3] = pk(a1.z, a1.w);
        Xh[q][4] = pk(a2.x, a2.y); Xh[q][5] = pk(a2.z, a2.w);
        Xh[q][6] = pk(a3.x, a3.y); Xh[q][7] = pk(a3.z, a3.w);
    }
    __syncthreads();

    unsigned* base = Dd + (size_t)n * 131072;
#pragma unroll
    for (int m = 0; m < 8; ++m) {
        const int tau = t0 + wq + 4 * m;
        const int j   = tau - p;
        if (j >= 0 && j < 512 && tau <= 766) {
            const int s = j - jb;                    // 0..94
            const uint4 z0 = ZL0[s], z1 = ZL1[s];
            const float zz = zs2[s];
            float a0 = 0.0f, a1 = 0.0f;
            a0 = FDOT2(z0.x, Xh[0][0], a0); a0 = FDOT2(z0.y, Xh[0][1], a0);
            a0 = FDOT2(z0.z, Xh[0][2], a0); a0 = FDOT2(z0.w, Xh[0][3], a0);
            a0 = FDOT2(z1.x, Xh[0][4], a0); a0 = FDOT2(z1.y, Xh[0][5], a0);
            a0 = FDOT2(z1.z, Xh[0][6], a0); a0 = FDOT2(z1.w, Xh[0][7], a0);
            a1 = FDOT2(z0.x, Xh[1][0], a1); a1 = FDOT2(z0.y, Xh[1][1], a1);
            a1 = FDOT2(z0.z, Xh[1][2], a1); a1 = FDOT2(z0.w, Xh[1][3], a1);
            a1 = FDOT2(z1.x, Xh[1][4], a1); a1 = FDOT2(z1.y, Xh[1][5], a1);
            a1 = FDOT2(z1.z, Xh[1][6], a1); a1 = FDOT2(z1.w, Xh[1][7], a1);
            const float dd0 = fmaf(M2L, a0, xs2[0] + zz);   // rows 2p, 2p+1
            const float dd1 = fmaf(M2L, a1, xs2[1] + zz);
            const int psh = (tau > 511) ? (tau - 511) : 0;
            base[dwoff(tau) + p - psh] = pk(dd0, dd1);
        }
    }
}

// ---------------------------------------------------------------------------
// Kernel 2: column-march banded (K,sm) SoftDTW DP (r10 structure) streaming
// precomputed D. 512 thr = 2 samples x 4 bands; 2 waves/SIMD hide stalls.
// Per tick per wave: 1 global dword (D pair, prefetched 4 ticks ahead),
// 2 shfl, 2 seam b32 reads, (K,sm) softmin. Borders exact via (BIGS,1)
// initialization (no repair code). Renorm (exact pow-2) every 8 ticks.
// ---------------------------------------------------------------------------
__global__ __launch_bounds__(512, 2) void k_dp(const unsigned* __restrict__ Dd,
                                               const float* __restrict__ w,
                                               float* __restrict__ out) {
    const int tt   = threadIdx.x;
    const int t    = tt & 63;
    const int band = (tt >> 6) & 3;
    const int samp = tt >> 8;
    const int n    = blockIdx.x * 2 + samp;

    __shared__ float sKr[2][4][64];      // seam rings (K); band0 = const border
    __shared__ float sSr[2][4][64];      // seam rings (sm)
    (&sKr[0][0][0])[tt] = BIGS;
    (&sSr[0][0][0])[tt] = 1.0f;
    const float wgt = w[n];
    const unsigned* base = Dd + (size_t)n * 131072;
    float* rK = &sKr[samp][band][0];
    float* rS = &sSr[samp][band][0];
    const int tgb = 64 * band;           // tau_global = tgb + tau_local
    __syncthreads();

    float RpK[2], RpS[2], poK, poS, smK, smS;
    unsigned ddq[4];
    RpK[0] = RpK[1] = BIGS; RpS[0] = RpS[1] = 1.0f;
    poK = BIGS; poS = 1.0f; smK = BIGS; smS = 1.0f;
    ddq[0] = ddq[1] = ddq[2] = ddq[3] = 0u;

    auto dload = [&](int tl) -> unsigned {
        int tg = tgb + tl; if (tg > 766) tg = 766;
        const int ln = glen(tg);
        int p = 64 * band + t - (tg > 511 ? tg - 511 : 0);
        p = p < 0 ? 0 : (p > ln - 1 ? ln - 1 : p);
        return base[dwoff(tg) + p];
    };

#define TICK(pp, tl)                                                           \
    {                                                                          \
        float unK = __shfl_up(RpK[1], 1);                                      \
        float unS = __shfl_up(RpS[1], 1);                                      \
        if (t == 0) { unK = smK; unS = smS; }                                  \
        smK = rK[((tl) + 1) & 63];           /* seam for next tick */          \
        smS = rS[((tl) + 1) & 63];                                             \
        const unsigned dw = ddq[pp];                                           \
        ddq[pp] = dload((tl) + 4);           /* prefetch 4 ticks ahead */      \
        const int j = (tl) - t;                                                \
        if (j >= 0 && j < 512) {                                               \
            const h2 hv = __builtin_bit_cast(h2, dw);                          \
            const float dd0 = (float)hv.x, dd1 = (float)hv.y;                  \
            /* cell0 (row 2p): up=(unK,unS) left=Rp[0] diag=(poK,poS) */       \
            const float l0K = RpK[0], l0S = RpS[0];                            \
            const float m0 = fminf(fminf(unK, l0K), poK);                      \
            const float s0 = exp2f(m0 - unK) * unS                             \
                           + exp2f(m0 - l0K) * l0S                             \
                           + exp2f(m0 - poK) * poS;                            \
            const float K0 = dd0 + m0;                                         \
            /* cell1 (row 2p+1): up=(K0,s0) left=Rp[1] diag=old Rp[0] */       \
            const float l1K = RpK[1], l1S = RpS[1];                            \
            const float m1 = fminf(fminf(K0, l1K), l0K);                       \
            const float s1 = exp2f(m1 - K0) * s0                               \
                           + exp2f(m1 - l1K) * l1S                             \
                           + exp2f(m1 - l0K) * l0S;                            \
            const float K1 = dd1 + m1;                                         \
            RpK[0] = K0; RpS[0] = s0;                                          \
            RpK[1] = K1; RpS[1] = s1;                                          \
            if (band < 3 && t == 63) {                                         \
                sKr[samp][band + 1][j & 63] = K1;                              \
                sSr[samp][band + 1][j & 63] = s1;                              \
            }                                                                  \
        }                                                                      \
        poK = unK; poS = unS;                                                  \
    }

#define RENORM                                                                 \
    {                                                                          \
        _Pragma("unroll")                                                      \
        for (int q = 0; q < 2; ++q) {                                          \
            const int e = (int)(__float_as_uint(RpS[q]) >> 23) - 127;          \
            RpS[q] = __uint_as_float(__float_as_uint(RpS[q])                   \
                                     - ((unsigned)e << 23));                   \
            RpK[q] -= (float)e;                                                \
        }                                                                      \
    }

#pragma unroll 1
    for (int s = 0; s < N_SS; ++s) {
        const int tb = P_SS * s - G_LAG * band;
        if (tb >= 0 && tb <= 574) {
            if (tb == 0) {
                RpK[0] = RpK[1] = BIGS; RpS[0] = RpS[1] = 1.0f;
                poK = (band == 0 && t == 0) ? 0.0f : BIGS; poS = 1.0f;
                smK = rK[0]; smS = rS[0];
                ddq[0] = dload(0); ddq[1] = dload(1);
                ddq[2] = dload(2); ddq[3] = dload(3);
            }
            TICK(0, tb + 0)  TICK(1, tb + 1)  TICK(2, tb + 2)  TICK(3, tb + 3)
            TICK(0, tb + 4)  TICK(1, tb + 5)  TICK(2, tb + 6)  TICK(3, tb + 7)
            RENORM
            TICK(0, tb + 8)  TICK(1, tb + 9)  TICK(2, tb + 10) TICK(3, tb + 11)
            TICK(0, tb + 12) TICK(1, tb + 13) TICK(2, tb + 14) TICK(3, tb + 15)
            RENORM
        }
        __syncthreads();
    }
#undef TICK
#undef RENORM

    // band 3, lane 63, row 511, tick 574 -> R(511,511) = K - log2(sm)
    if (band == 3 && t == 63) {
        atomicAdd(out, wgt * (RpK[1] - log2f(RpS[1])) * LN2F);
    }
}

extern "C" void kernel_launch(void* const* d_in, const int* in_sizes, int n_in,
                              void* d_out, int out_size, void* d_ws, size_t ws_size,
                              hipStream_t stream) {
    const float* X = (const float*)d_in[0];   // (64, 512, 16) f32
    const float* w = (const float*)d_in[1];   // (64,) f32
    const float* Z = (const float*)d_in[2];   // (512, 16) f32
    float* out = (float*)d_out;               // scalar f32
    unsigned* Dd = (unsigned*)d_ws;           // 64 x 131072 dwords = 32 MiB

    hipLaunchKernelGGL(k_dist, dim3(64, 4, 24), dim3(256), 0, stream, X, Z, Dd, out);
    hipLaunchKernelGGL(k_dp, dim3(32), dim3(512), 0, stream, Dd, w, out);
}

// Round 12
// 256.643 us; speedup vs baseline: 1.5545x; 1.5545x over previous
//
#include <hip/hip_runtime.h>

#define TT 512
#define BIGS 1.4426950408889634e10f   // BIG(1e10) * log2(e), scaled domain
#define LOG2E 1.4426950408889634f
#define M2L  (-2.0f * 1.4426950408889634f)
#define LN2F 0.69314718055994531f
#define P_SS 16                       // ticks per superstep (barrier period)
#define G_LAG 80                      // band lag in ticks (>= P_SS + 63 + 1)
#define N_SS 51                       // band3 last tick 574 at s=50

typedef _Float16 h2 __attribute__((ext_vector_type(2)));

__device__ __forceinline__ unsigned pk(float a, float b) {
    h2 v; v.x = (_Float16)a; v.y = (_Float16)b;
    return __builtin_bit_cast(unsigned, v);
}

#if __has_builtin(__builtin_amdgcn_fdot2)
#define FDOT2(a, b, c) __builtin_amdgcn_fdot2(__builtin_bit_cast(h2, (a)), \
                                              __builtin_bit_cast(h2, (b)), (c), false)
#else
__device__ __forceinline__ float fdot2_sw(unsigned a, unsigned b, float c) {
    h2 ha = __builtin_bit_cast(h2, a), hb = __builtin_bit_cast(h2, b);
    return c + (float)ha.x * (float)hb.x + (float)ha.y * (float)hb.y;
}
#define FDOT2(a, b, c) fdot2_sw((a), (b), (c))
#endif

// permuted Z index, pure bitops (valid for any int j; wraps out-of-range j
// onto some valid row -- garbage rows only feed inactive ticks)
#define ZROW(jv) (((((jv) & 1)) << 8) | ((((jv) >> 1)) & 255))

// ---------------------------------------------------------------------------
// Banded column-marching fused SoftDTW in (K, sm) split form -- round 10
// structure with tick-latency surgery:
//  * boundary shfl issued at END of tick tau (post-select), consumed at
//    tau+1 -> ds_permute latency off the softmin chain head
//  * j-guard flattened to cndmask selects on the state writes (softmin runs
//    unconditionally on finite data) -> no exec branches in the tick body
//  * Z-row index = bitops (no clamps); prefetch distance 2 unchanged
// Schedule, seam rings, renorm, borders: identical to round 10 (verified).
// ---------------------------------------------------------------------------
__global__ __launch_bounds__(256, 1) void k_fused(const float* __restrict__ X,
                                                  const float* __restrict__ Z,
                                                  const float* __restrict__ w,
                                                  float* __restrict__ out) {
    const int tt = threadIdx.x;
    const int t  = tt & 63;          // lane
    const int wv = tt >> 6;          // wave = row band 0..3
    const int n  = blockIdx.x;       // sample

    __shared__ uint4 ZA[2][512];     // Z rows fp16-packed, permuted idx
    __shared__ float Zs2p[512];      // LOG2E*|z|^2 at permuted idx
    __shared__ float seamK[4][64];   // seam rings (K); band0 = const border
    __shared__ float seamS[4][64];   // seam rings (sm)

    // ---- stage Z into LDS: thread tt handles rows tt, tt+256 ----
#pragma unroll
    for (int h = 0; h < 2; ++h) {
        const int r = tt + h * 256;
        const float4* zp = (const float4*)(Z + (size_t)r * 16);
        const float4 a0 = zp[0], a1 = zp[1], a2 = zp[2], a3 = zp[3];
        float sv = 0.0f;
        sv = fmaf(a0.x, a0.x, sv); sv = fmaf(a0.y, a0.y, sv);
        sv = fmaf(a0.z, a0.z, sv); sv = fmaf(a0.w, a0.w, sv);
        sv = fmaf(a1.x, a1.x, sv); sv = fmaf(a1.y, a1.y, sv);
        sv = fmaf(a1.z, a1.z, sv); sv = fmaf(a1.w, a1.w, sv);
        sv = fmaf(a2.x, a2.x, sv); sv = fmaf(a2.y, a2.y, sv);
        sv = fmaf(a2.z, a2.z, sv); sv = fmaf(a2.w, a2.w, sv);
        sv = fmaf(a3.x, a3.x, sv); sv = fmaf(a3.y, a3.y, sv);
        sv = fmaf(a3.z, a3.z, sv); sv = fmaf(a3.w, a3.w, sv);
        const int idx = ((r & 1) << 8) | (r >> 1);
        ZA[0][idx] = make_uint4(pk(a0.x, a0.y), pk(a0.z, a0.w),
                                pk(a1.x, a1.y), pk(a1.z, a1.w));
        ZA[1][idx] = make_uint4(pk(a2.x, a2.y), pk(a2.z, a2.w),
                                pk(a3.x, a3.y), pk(a3.z, a3.w));
        Zs2p[idx] = LOG2E * sv;
    }
    // seam rings -> (BIGS, 1): matrix border; band 0 ring is never written
    (&seamK[0][0])[tt] = BIGS;
    (&seamS[0][0])[tt] = 1.0f;

    // ---- X rows for this lane (rows i0, i0+1) -> registers ----
    const int i0 = 128 * wv + 2 * t;
    unsigned Xu[2][8];
    float    xs2[2];
    const float* xp = X + ((size_t)n * TT + i0) * 16;
#pragma unroll
    for (int q = 0; q < 2; ++q) {
        const float4* xr = (const float4*)(xp + q * 16);
        const float4 a0 = xr[0], a1 = xr[1], a2 = xr[2], a3 = xr[3];
        float sv = 0.0f;
        sv = fmaf(a0.x, a0.x, sv); sv = fmaf(a0.y, a0.y, sv);
        sv = fmaf(a0.z, a0.z, sv); sv = fmaf(a0.w, a0.w, sv);
        sv = fmaf(a1.x, a1.x, sv); sv = fmaf(a1.y, a1.y, sv);
        sv = fmaf(a1.z, a1.z, sv); sv = fmaf(a1.w, a1.w, sv);
        sv = fmaf(a2.x, a2.x, sv); sv = fmaf(a2.y, a2.y, sv);
        sv = fmaf(a2.z, a2.z, sv); sv = fmaf(a2.w, a2.w, sv);
        sv = fmaf(a3.x, a3.x, sv); sv = fmaf(a3.y, a3.y, sv);
        sv = fmaf(a3.z, a3.z, sv); sv = fmaf(a3.w, a3.w, sv);
        xs2[q] = LOG2E * sv;
        Xu[q][0] = pk(a0.x, a0.y); Xu[q][1] = pk(a0.z, a0.w);
        Xu[q][2] = pk(a1.x, a1.y); Xu[q][3] = pk(a1.z, a1.w);
        Xu[q][4] = pk(a2.x, a2.y); Xu[q][5] = pk(a2.z, a2.w);
        Xu[q][6] = pk(a3.x, a3.y); Xu[q][7] = pk(a3.z, a3.w);
    }
    const float wgt = w[n];
    const float* rK = &seamK[wv][0];
    const float* rS = &seamS[wv][0];
    __syncthreads();

    float RpK[2], RpS[2], poK, poS, smK, smS, bnK, bnS;
    uint4 Zb[2][2];
    float zsb[2];
    RpK[0] = RpK[1] = BIGS; RpS[0] = RpS[1] = 1.0f;
    poK = BIGS; poS = 1.0f; smK = BIGS; smS = 1.0f;
    bnK = BIGS; bnS = 1.0f;
    zsb[0] = zsb[1] = 0.0f;
    Zb[0][0] = Zb[0][1] = Zb[1][0] = Zb[1][1] = make_uint4(0, 0, 0, 0);

#define TICK(par, tl)                                                          \
    {                                                                          \
        const float unK = (t == 0) ? smK : bnK;                                \
        const float unS = (t == 0) ? smS : bnS;                                \
        smK = rK[((tl) + 1) & 63];           /* seam for next tick */          \
        smS = rS[((tl) + 1) & 63];                                             \
        const uint4 z0 = Zb[par][0], z1 = Zb[par][1];                          \
        const float zz = zsb[par];                                             \
        {   /* refill this slot with the row for tick tl+2 */                  \
            const int xn = ZROW((tl) + 2 - t);                                 \
            Zb[par][0] = ZA[0][xn];                                            \
            Zb[par][1] = ZA[1][xn];                                            \
            zsb[par] = Zs2p[xn];                                               \
        }                                                                      \
        float a0 = 0.0f, a1 = 0.0f;                                            \
        a0 = FDOT2(z0.x, Xu[0][0], a0); a0 = FDOT2(z0.y, Xu[0][1], a0);        \
        a0 = FDOT2(z0.z, Xu[0][2], a0); a0 = FDOT2(z0.w, Xu[0][3], a0);        \
        a0 = FDOT2(z1.x, Xu[0][4], a0); a0 = FDOT2(z1.y, Xu[0][5], a0);        \
        a0 = FDOT2(z1.z, Xu[0][6], a0); a0 = FDOT2(z1.w, Xu[0][7], a0);        \
        a1 = FDOT2(z0.x, Xu[1][0], a1); a1 = FDOT2(z0.y, Xu[1][1], a1);        \
        a1 = FDOT2(z0.z, Xu[1][2], a1); a1 = FDOT2(z0.w, Xu[1][3], a1);        \
        a1 = FDOT2(z1.x, Xu[1][4], a1); a1 = FDOT2(z1.y, Xu[1][5], a1);        \
        a1 = FDOT2(z1.z, Xu[1][6], a1); a1 = FDOT2(z1.w, Xu[1][7], a1);        \
        const float dd0 = fmaf(M2L, a0, xs2[0] + zz);                          \
        const float dd1 = fmaf(M2L, a1, xs2[1] + zz);                          \
        /* (K,sm) softmin, unconditional (all operands finite) */              \
        const float l0K = RpK[0], l0S = RpS[0];                                \
        const float m0 = fminf(fminf(unK, l0K), poK);                          \
        const float s0 = exp2f(m0 - unK) * unS                                 \
                       + exp2f(m0 - l0K) * l0S                                 \
                       + exp2f(m0 - poK) * poS;                                \
        const float K0 = dd0 + m0;                                             \
        const float l1K = RpK[1], l1S = RpS[1];                                \
        const float m1 = fminf(fminf(K0, l1K), l0K);                           \
        const float s1 = exp2f(m1 - K0) * s0                                   \
                       + exp2f(m1 - l1K) * l1S                                 \
                       + exp2f(m1 - l0K) * l0S;                                \
        const float K1 = dd1 + m1;                                             \
        const int j = (tl) - t;                                                \
        const bool ok = (j >= 0) && (j < 512);                                 \
        RpK[0] = ok ? K0 : RpK[0];  RpS[0] = ok ? s0 : RpS[0];                 \
        RpK[1] = ok ? K1 : RpK[1];  RpS[1] = ok ? s1 : RpS[1];                 \
        if (ok && wv < 3 && t == 63) {                                         \
            seamK[wv + 1][j & 63] = RpK[1];                                    \
            seamS[wv + 1][j & 63] = RpS[1];                                    \
        }                                                                      \
        poK = unK; poS = unS;                                                  \
        bnK = __shfl_up(RpK[1], 1);          /* boundary for tick tl+1 */      \
        bnS = __shfl_up(RpS[1], 1);                                            \
    }

#define RENORM                                                                 \
    {                                                                          \
        _Pragma("unroll")                                                      \
        for (int q = 0; q < 2; ++q) {                                          \
            const int e = (int)(__float_as_uint(RpS[q]) >> 23) - 127;          \
            RpS[q] = __uint_as_float(__float_as_uint(RpS[q])                   \
                                     - ((unsigned)e << 23));                   \
            RpK[q] -= (float)e;                                                \
        }                                                                      \
    }

#pragma unroll 1
    for (int s = 0; s < N_SS; ++s) {
        const int tb = P_SS * s - G_LAG * wv;
        if (tb >= 0 && tb <= 574) {
            if (tb == 0) {
                // activation: state + boundary + Z buffers for ticks 0,1
                RpK[0] = RpK[1] = BIGS; RpS[0] = RpS[1] = 1.0f;
                poK = (wv == 0 && t == 0) ? 0.0f : BIGS; poS = 1.0f;  // corner
                bnK = BIGS; bnS = 1.0f;
                smK = rK[0]; smS = rS[0];
                const int x0 = ZROW(0 - t);
                const int x1 = ZROW(1 - t);
                Zb[0][0] = ZA[0][x0]; Zb[0][1] = ZA[1][x0]; zsb[0] = Zs2p[x0];
                Zb[1][0] = ZA[0][x1]; Zb[1][1] = ZA[1][x1]; zsb[1] = Zs2p[x1];
            }
            TICK(0, tb + 0)  TICK(1, tb + 1)  TICK(0, tb + 2)  TICK(1, tb + 3)
            TICK(0, tb + 4)  TICK(1, tb + 5)  TICK(0, tb + 6)  TICK(1, tb + 7)
            RENORM
            TICK(0, tb + 8)  TICK(1, tb + 9)  TICK(0, tb + 10) TICK(1, tb + 11)
            TICK(0, tb + 12) TICK(1, tb + 13) TICK(0, tb + 14) TICK(1, tb + 15)
            RENORM
        }
        __syncthreads();
    }
#undef TICK
#undef RENORM

    // band 3, lane 63, row 511 at tick 574 -> R(511,511) = K - log2(sm)
    if (wv == 3 && t == 63) {
        atomicAdd(out, wgt * (RpK[1] - log2f(RpS[1])) * LN2F);
    }
}

__global__ void k_zero(float* out) {
    if (threadIdx.x == 0) out[0] = 0.0f;
}

extern "C" void kernel_launch(void* const* d_in, const int* in_sizes, int n_in,
                              void* d_out, int out_size, void* d_ws, size_t ws_size,
                              hipStream_t stream) {
    const float* X = (const float*)d_in[0];   // (64, 512, 16) f32
    const float* w = (const float*)d_in[1];   // (64,) f32
    const float* Z = (const float*)d_in[2];   // (512, 16) f32
    float* out = (float*)d_out;               // scalar f32

    hipLaunchKernelGGL(k_zero, dim3(1), dim3(64), 0, stream, out);
    hipLaunchKernelGGL(k_fused, dim3(64), dim3(256), 0, stream, X, Z, w, out);
}